// Round 2
// baseline (33212.527 us; speedup 1.0000x reference)
//
#include <hip/hip_runtime.h>
#include <stdint.h>
#include <stddef.h>

// ---------------- problem constants ----------------
static constexpr int N    = 100000;
static constexpr int HID  = 256;
static constexpr int IEMB = 128;
static constexpr int NNZ  = 3200000;
static constexpr int OUTW = 3 * HID + IEMB;  // 896
static constexpr float NEG_SLOPE = 0.2f;

// JAX threefry variant: 1 = partitionable (default in JAX >= 0.5.0), 0 = original
#define THREEFRY_PARTITIONABLE 1

// ---------------- threefry2x32 (JAX-compatible) ----------------
__host__ __device__ inline uint32_t rotl32(uint32_t v, int r) {
  return (v << r) | (v >> (32 - r));
}

__host__ __device__ inline void threefry2x32(uint32_t k0, uint32_t k1,
                                             uint32_t x0, uint32_t x1,
                                             uint32_t& o0, uint32_t& o1) {
  const uint32_t k2 = k0 ^ k1 ^ 0x1BD11BDAu;
  x0 += k0; x1 += k1;
  // rounds 1-4
  x0 += x1; x1 = rotl32(x1, 13); x1 ^= x0;
  x0 += x1; x1 = rotl32(x1, 15); x1 ^= x0;
  x0 += x1; x1 = rotl32(x1, 26); x1 ^= x0;
  x0 += x1; x1 = rotl32(x1,  6); x1 ^= x0;
  x0 += k1; x1 += k2 + 1u;
  // rounds 5-8
  x0 += x1; x1 = rotl32(x1, 17); x1 ^= x0;
  x0 += x1; x1 = rotl32(x1, 29); x1 ^= x0;
  x0 += x1; x1 = rotl32(x1, 16); x1 ^= x0;
  x0 += x1; x1 = rotl32(x1, 24); x1 ^= x0;
  x0 += k2; x1 += k0 + 2u;
  // rounds 9-12
  x0 += x1; x1 = rotl32(x1, 13); x1 ^= x0;
  x0 += x1; x1 = rotl32(x1, 15); x1 ^= x0;
  x0 += x1; x1 = rotl32(x1, 26); x1 ^= x0;
  x0 += x1; x1 = rotl32(x1,  6); x1 ^= x0;
  x0 += k0; x1 += k1 + 3u;
  // rounds 13-16
  x0 += x1; x1 = rotl32(x1, 17); x1 ^= x0;
  x0 += x1; x1 = rotl32(x1, 29); x1 ^= x0;
  x0 += x1; x1 = rotl32(x1, 16); x1 ^= x0;
  x0 += x1; x1 = rotl32(x1, 24); x1 ^= x0;
  x0 += k1; x1 += k2 + 4u;
  // rounds 17-20
  x0 += x1; x1 = rotl32(x1, 13); x1 ^= x0;
  x0 += x1; x1 = rotl32(x1, 15); x1 ^= x0;
  x0 += x1; x1 = rotl32(x1, 26); x1 ^= x0;
  x0 += x1; x1 = rotl32(x1,  6); x1 ^= x0;
  x0 += k2; x1 += k0 + 5u;
  o0 = x0; o1 = x1;
}

// keep-mask for flat element index e of a [N,HID] dropout draw under key (k0,k1)
__device__ inline bool keep_elem(uint32_t k0, uint32_t k1, uint32_t e) {
  uint32_t o0, o1, bits;
#if THREEFRY_PARTITIONABLE
  threefry2x32(k0, k1, 0u, e, o0, o1);   // counter = 64-bit flat index (hi=0, lo=e)
  bits = o0 ^ o1;                        // 32-bit draw folds the two output words
#else
  const uint32_t H = (uint32_t)(N) * (uint32_t)(HID) / 2u;  // 12,800,000
  if (e < H) { threefry2x32(k0, k1, e, e + H, o0, o1); bits = o0; }
  else       { threefry2x32(k0, k1, e - H, e, o0, o1); bits = o1; }
#endif
  float u = __uint_as_float((bits >> 9) | 0x3f800000u) - 1.0f;  // [0,1)
  return u < 0.9f;  // bernoulli(keep=0.9): uniform < p
}

// ---------------- kernels (all float32) ----------------

// x = embed[x_idx]; write f32 copy to A (stride HID) and to out cols [0,256)
__global__ __launch_bounds__(256) void k_gather(const int* __restrict__ xidx,
                                                const float* __restrict__ emb,
                                                float* __restrict__ A,
                                                float* __restrict__ out) {
  int t = blockIdx.x * 256 + threadIdx.x;          // over N*64 chunks of 4 elems
  int n = t >> 6;
  int c4 = (t & 63) * 4;
  if (n >= N) return;
  int src = xidx[n];
  float4 v = *(const float4*)(emb + (size_t)src * HID + c4);
  *(float4*)(out + (size_t)n * OUTW + c4) = v;
  *(float4*)(A + (size_t)n * HID + c4) = v;
}

__global__ __launch_bounds__(256) void k_zero(float4* __restrict__ p, int n4) {
  int i = blockIdx.x * 256 + threadIdx.x;
  if (i < n4) p[i] = make_float4(0.f, 0.f, 0.f, 0.f);
}

// edge-parallel SpMM: B[r] += v * A[c]; one wave (64 lanes) per edge, 4 floats/lane
__global__ __launch_bounds__(256) void k_spmm(const int* __restrict__ rows,
                                              const int* __restrict__ cols,
                                              const float* __restrict__ vals,
                                              const float* __restrict__ A,
                                              float* __restrict__ B) {
  int e = blockIdx.x * 4 + (threadIdx.x >> 6);
  int lane = threadIdx.x & 63;
  if (e >= NNZ) return;
  int r = rows[e];
  int c = cols[e];
  float v = vals[e];
  float4 x = *(const float4*)(A + (size_t)c * HID + lane * 4);
  float* bp = B + (size_t)r * HID + lane * 4;
  unsafeAtomicAdd(bp + 0, v * x.x);  // HW global_atomic_add_f32, device scope
  unsafeAtomicAdd(bp + 1, v * x.y);
  unsafeAtomicAdd(bp + 2, v * x.z);
  unsafeAtomicAdd(bp + 3, v * x.w);
}

// B <- dropout(B + A) with JAX-exact mask
__global__ __launch_bounds__(256) void k_dropres(const float* __restrict__ A,
                                                 float* __restrict__ B,
                                                 uint32_t k0, uint32_t k1) {
  uint32_t e = blockIdx.x * 256 + threadIdx.x;
  if (e >= (uint32_t)N * HID) return;
  float m = B[e] + A[e];
  B[e] = keep_elem(k0, k1, e) ? (m / 0.9f) : 0.0f;
}

// h' = leaky(M @ W^T + b); M is [N,HID] f32, W is [NC,HID] f32 row-major.
// 64-row tile per block; m staged to LDS as [k][r] (broadcast b128 reads);
// W columns held in registers (4 contiguous output cols per thread).
template <int NC, bool WRITE_F32>
__global__ __launch_bounds__(256) void k_gemm(const float* __restrict__ M,
                                              const float* __restrict__ W,
                                              const float* __restrict__ bias,
                                              float* __restrict__ Aout,
                                              float* __restrict__ out,
                                              int colbase) {
  constexpr int CG = NC / 4;    // col groups (64 or 32)
  constexpr int RG = 256 / CG;  // row groups (4 or 8)
  constexpr int RPT = 64 / RG;  // rows per thread (16 or 8)
  __shared__ float m_s[64][68]; // [k][r]; pad keeps 16B alignment

  const int tid = threadIdx.x;
  const int j = tid % CG;       // this thread's col group -> cols 4j..4j+3
  const int rg = tid / CG;
  const int row0 = blockIdx.x * 64;
  const int r0 = rg * RPT;

  float acc[RPT][4];
#pragma unroll
  for (int i = 0; i < RPT; ++i)
#pragma unroll
    for (int c = 0; c < 4; ++c) acc[i][c] = 0.f;

  const int rr = tid >> 4;         // 0..15
  const int kk = (tid & 15) * 4;   // 0..60

#pragma unroll 1
  for (int kc = 0; kc < HID; kc += 64) {
    __syncthreads();
    // stage M[row0:row0+64, kc:kc+64] transposed into m_s[k][r]
#pragma unroll
    for (int p = 0; p < 4; ++p) {
      int r = p * 16 + rr;
      int grow = row0 + r;
      float4 v = make_float4(0.f, 0.f, 0.f, 0.f);
      if (grow < N) v = *(const float4*)(M + (size_t)grow * HID + kc + kk);
      m_s[kk + 0][r] = v.x;
      m_s[kk + 1][r] = v.y;
      m_s[kk + 2][r] = v.z;
      m_s[kk + 3][r] = v.w;
    }
    __syncthreads();

#pragma unroll 1
    for (int ks = 0; ks < 64; ks += 8) {
      float4 wa[4], wb[4];  // 8 f32 along k for each of 4 cols
#pragma unroll
      for (int c = 0; c < 4; ++c) {
        const float* wp = W + (size_t)(4 * j + c) * HID + kc + ks;
        wa[c] = *(const float4*)(wp);
        wb[c] = *(const float4*)(wp + 4);
      }
#pragma unroll
      for (int q = 0; q < 8; ++q) {
        float wf[4];
#pragma unroll
        for (int c = 0; c < 4; ++c) {
          const float* wv = (q < 4) ? (const float*)&wa[c] : (const float*)&wb[c];
          wf[c] = wv[q & 3];
        }
        const float* ms = &m_s[ks + q][r0];
#pragma unroll
        for (int ii = 0; ii < RPT / 4; ++ii) {
          float4 mv = *(const float4*)(ms + ii * 4);  // broadcast within row group
          const float mr[4] = {mv.x, mv.y, mv.z, mv.w};
#pragma unroll
          for (int t = 0; t < 4; ++t)
#pragma unroll
            for (int c = 0; c < 4; ++c)
              acc[ii * 4 + t][c] = fmaf(mr[t], wf[c], acc[ii * 4 + t][c]);
        }
      }
    }
  }

  float bv[4];
#pragma unroll
  for (int c = 0; c < 4; ++c) bv[c] = bias[4 * j + c];

#pragma unroll
  for (int i = 0; i < RPT; ++i) {
    int grow = row0 + r0 + i;
    if (grow < N) {
      float4 ov;
      float* ovp = (float*)&ov;
#pragma unroll
      for (int c = 0; c < 4; ++c) {
        float v = acc[i][c] + bv[c];
        ovp[c] = (v >= 0.f) ? v : NEG_SLOPE * v;
      }
      if (WRITE_F32)
        *(float4*)(Aout + (size_t)grow * HID + 4 * j) = ov;
      *(float4*)(out + (size_t)grow * OUTW + colbase + 4 * j) = ov;
    }
  }
}

// ---------------- host launcher ----------------
extern "C" void kernel_launch(void* const* d_in, const int* in_sizes, int n_in,
                              void* d_out, int out_size, void* d_ws, size_t ws_size,
                              hipStream_t stream) {
  (void)in_sizes; (void)n_in; (void)out_size; (void)ws_size;

  const int*   x_idx  = (const int*)d_in[0];
  const float* emb    = (const float*)d_in[1];
  const int*   g_rows = (const int*)d_in[2];
  const int*   g_cols = (const int*)d_in[3];
  const float* g_vals = (const float*)d_in[4];
  const float* W1 = (const float*)d_in[5];
  const float* b1 = (const float*)d_in[6];
  const float* W2 = (const float*)d_in[7];
  const float* b2 = (const float*)d_in[8];
  const float* W3 = (const float*)d_in[9];
  const float* b3 = (const float*)d_in[10];
  float* out = (float*)d_out;

  float* A = (float*)d_ws;                 // current layer input h  [N,HID] f32
  float* B = A + (size_t)N * HID;          // spmm accumulator / m   [N,HID] f32

  // dropout keys: dk = split(key(42), 3), reproduced host-side
  uint32_t dk[3][2];
#if THREEFRY_PARTITIONABLE
  for (uint32_t i = 0; i < 3; ++i)
    threefry2x32(0u, 42u, 0u, i, dk[i][0], dk[i][1]);
#else
  {
    uint32_t a0, c0, a1, c1, a2, c2;
    threefry2x32(0u, 42u, 0u, 3u, a0, c0);
    threefry2x32(0u, 42u, 1u, 4u, a1, c1);
    threefry2x32(0u, 42u, 2u, 5u, a2, c2);
    dk[0][0] = a0; dk[0][1] = a1;
    dk[1][0] = a2; dk[1][1] = c0;
    dk[2][0] = c1; dk[2][1] = c2;
  }
#endif

  const int gemm_blocks = (N + 63) / 64;   // 1563

  k_gather<<<(N * 64) / 256, 256, 0, stream>>>(x_idx, emb, A, out);

  const float* Ws[3] = {W1, W2, W3};
  const float* bs[3] = {b1, b2, b3};
  for (int l = 0; l < 3; ++l) {
    k_zero<<<(N * HID / 4 + 255) / 256, 256, 0, stream>>>((float4*)B, N * HID / 4);
    k_spmm<<<NNZ / 4, 256, 0, stream>>>(g_rows, g_cols, g_vals, A, B);
    k_dropres<<<(N * HID) / 256, 256, 0, stream>>>(A, B, dk[l][0], dk[l][1]);
    if (l < 2)
      k_gemm<HID, true><<<gemm_blocks, 256, 0, stream>>>(B, Ws[l], bs[l], A, out, HID * (l + 1));
    else
      k_gemm<IEMB, false><<<gemm_blocks, 256, 0, stream>>>(B, Ws[2], bs[2], nullptr, out, 3 * HID);
  }
}